// Round 1
// 278.536 us; speedup vs baseline: 1.1691x; 1.1691x over previous
//
#include <hip/hip_runtime.h>

#define N_NODES 100000
#define N_EDGES 1600000
#define D 128
#define MAXDEG 48

#define GEMM_NB ((N_NODES + 63) / 64)          // 1563 gemm blocks (64 rows each)
#define HIST_NB (N_EDGES / 256)                // 6250 hist blocks
#define TOTAL_NB (GEMM_NB + HIST_NB)           // 7813

typedef __attribute__((ext_vector_type(8))) short short8;
typedef __attribute__((ext_vector_type(4))) short short4v;
typedef __attribute__((ext_vector_type(4))) float floatx4;
typedef __attribute__((ext_vector_type(2))) float floatx2;

__device__ __forceinline__ short f2bf(float f) {
    unsigned u = __float_as_uint(f);
    u += 0x7FFFu + ((u >> 16) & 1u);           // round-nearest-even
    return (short)(u >> 16);
}

// ---------------------------------------------------------------------------
// Fused kernel, R5 structure: blocks interleaved 1 gemm : 4 hist by bid%5.
// R9 change: pairs store is PLAIN (was NT). NT forced per-8B-store line
// eviction -> 102 MB random 64B HBM writes (WRITE_SIZE 125 MB vs 38 MB
// useful). Plain store lets L2 merge a row's ~16 entries (2 lines) before
// writeback and keeps pairs L2/L3-resident for the gather.
// ---------------------------------------------------------------------------
#define LDSK 136
__global__ __launch_bounds__(256) void gemm_hist_fill(const float* __restrict__ x,
                                                      const float* __restrict__ mask,
                                                      const float* __restrict__ w,
                                                      unsigned short* __restrict__ h,
                                                      const int* __restrict__ erow,
                                                      const int* __restrict__ ecol,
                                                      const float* __restrict__ eval,
                                                      int* __restrict__ deg,
                                                      unsigned long long* __restrict__ pairs) {
    const unsigned bid = blockIdx.x;
    const int t = threadIdx.x;

    if (bid % 5 != 0) {
        // ---- hist + fill role ----
        const int hi = (int)(bid - bid / 5 - 1);
        const int e = hi * 256 + t;
        const int r = erow[e];
        const int k = atomicAdd(&deg[r], 1);
        if (k < MAXDEG) {
            const unsigned long long pv =
                (unsigned long long)(unsigned)ecol[e] |
                ((unsigned long long)(unsigned)__float_as_uint(eval[e]) << 32);
            pairs[(size_t)r * MAXDEG + k] = pv;   // plain store: L2 merges row's lines
        }
        return;
    }
    const int gb = (int)(bid / 5);             // gemm block index 0..GEMM_NB-1

    // ---- GEMM role ----
    __shared__ short w_s[128 * LDSK];          // 34816 B
#pragma unroll
    for (int i = 0; i < 4; ++i) {
        const int id = t + 256 * i;
        const int n0 = (id & 31) * 4;
        const int k0 = (id >> 5) * 4;
        short tr[4][4];
#pragma unroll
        for (int r = 0; r < 4; ++r) {
            const float4 wv = *(const float4*)(w + (size_t)(k0 + r) * D + n0);
            tr[r][0] = f2bf(wv.x); tr[r][1] = f2bf(wv.y);
            tr[r][2] = f2bf(wv.z); tr[r][3] = f2bf(wv.w);
        }
#pragma unroll
        for (int c = 0; c < 4; ++c) {
            short4v v = {tr[0][c], tr[1][c], tr[2][c], tr[3][c]};
            *(short4v*)(&w_s[(n0 + c) * LDSK + k0]) = v;
        }
    }
    __syncthreads();

    const int wave = t >> 6, lane = t & 63;
    const int m = lane & 15, quad = lane >> 4;
    const int r0w = gb * 64 + wave * 16;
    int arow = r0w + m;
    if (arow >= N_NODES) arow = N_NODES - 1;   // tail clamp (stores guarded below)
    const floatx4* xp4 = (const floatx4*)(x + (size_t)arow * D);
    const floatx4* mp4 = (const floatx4*)(mask + (size_t)arow * D);

    floatx4 acc[8];
#pragma unroll
    for (int tt = 0; tt < 8; ++tt) acc[tt] = (floatx4){0.f, 0.f, 0.f, 0.f};

#pragma unroll
    for (int kc = 0; kc < 4; ++kc) {
        const int kb = kc * 32 + quad * 8;     // lane's 8-k slice (in floats)
        const floatx4 xa = __builtin_nontemporal_load(xp4 + kb / 4);     // read-once
        const floatx4 xb = __builtin_nontemporal_load(xp4 + kb / 4 + 1);
        const floatx4 ma = __builtin_nontemporal_load(mp4 + kb / 4);
        const floatx4 mb = __builtin_nontemporal_load(mp4 + kb / 4 + 1);
        short8 a;
#pragma unroll
        for (int j = 0; j < 4; ++j) a[j] = f2bf(xa[j] * ma[j]);
#pragma unroll
        for (int j = 0; j < 4; ++j) a[4 + j] = f2bf(xb[j] * mb[j]);
#pragma unroll
        for (int tt = 0; tt < 8; ++tt) {
            const short8 bfrag = *(const short8*)(&w_s[(tt * 16 + m) * LDSK + kb]);
            acc[tt] = __builtin_amdgcn_mfma_f32_16x16x32_bf16(a, bfrag, acc[tt], 0, 0, 0);
        }
    }

    __syncthreads();
    // epilogue transpose through LDS (wave-private 16x136 tile aliasing w_s)
    short* ep = w_s + wave * 16 * LDSK;
#pragma unroll
    for (int tt = 0; tt < 8; ++tt) {
        const int col = tt * 16 + m;
#pragma unroll
        for (int i = 0; i < 4; ++i)             // C/D: col=lane&15, row=quad*4+i
            ep[(quad * 4 + i) * LDSK + col] = f2bf(acc[tt][i]);
    }
    __syncthreads();

    const int rrow = lane >> 2;
    const int chunk = lane & 3;
    const int gr = r0w + rrow;
    if (gr < N_NODES) {
        const short* src = ep + rrow * LDSK + chunk * 32;
        unsigned short* dst = h + (size_t)gr * D + chunk * 32;
#pragma unroll
        for (int j = 0; j < 4; ++j)
            *(short8*)(dst + j * 8) = *(const short8*)(src + j * 8);
    }
}

// ---------------------------------------------------------------------------
// Gather-aggregate, R9 restructure: ONE 64-lane vector load fetches the
// whole padded pair-list of a row (48 entries <= 64 lanes); per-edge col/val
// come from __builtin_amdgcn_readlane (uniform j) -> SGPRs. This removes the
// per-batch pairs-load from the dependency chain (h addresses are scalar,
// no memory dependency), strips the VGPR address math, and lets consecutive
// batches' h loads issue back-to-back (deep vmcnt pipeline). Tail lanes are
// branchless: col/val cselect'd to 0, dummy loads hit one cached line.
// Two rows per wave as before (16 independent h loads per batch pair).
// ---------------------------------------------------------------------------
__global__ __launch_bounds__(256) void gather_kernel(const unsigned* __restrict__ h2,
                                                     const int* __restrict__ deg,
                                                     const unsigned long long* __restrict__ pairs,
                                                     const float* __restrict__ b,
                                                     float* __restrict__ out) {
    const int lane = threadIdx.x & 63;
    const int rA = blockIdx.x * 8 + (threadIdx.x >> 6) * 2;   // wave's row pair
    const int rB = rA + 1;

    int dgA = deg[rA]; if (dgA > MAXDEG) dgA = MAXDEG;
    int dgB = deg[rB]; if (dgB > MAXDEG) dgB = MAXDEG;

    // one vector load per row grabs the entire padded pair list into lanes
    const int pl = (lane < MAXDEG) ? lane : (MAXDEG - 1);
    const unsigned long long pvA = pairs[(size_t)rA * MAXDEG + pl];
    const unsigned long long pvB = pairs[(size_t)rB * MAXDEG + pl];
    const unsigned cAv = (unsigned)pvA;          // lane-held col bits (row A)
    const unsigned wAv = (unsigned)(pvA >> 32);  // lane-held val bits (row A)
    const unsigned cBv = (unsigned)pvB;
    const unsigned wBv = (unsigned)(pvB >> 32);

    float axA = 0.f, ayA = 0.f, axB = 0.f, ayB = 0.f;
    const int mx = (dgA > dgB) ? dgA : dgB;

    for (int b0 = 0; b0 < mx; b0 += 8) {
        unsigned uA[8], uB[8];
        float vA[8], vB[8];
#pragma unroll
        for (int jj = 0; jj < 8; ++jj) {
            const int j = b0 + jj;
            // uniform (SGPR) col/val; guarded cselect keeps dummy loads at row 0
            const unsigned colA = (j < dgA)
                ? (unsigned)__builtin_amdgcn_readlane((int)cAv, j) : 0u;
            vA[jj] = (j < dgA)
                ? __uint_as_float((unsigned)__builtin_amdgcn_readlane((int)wAv, j)) : 0.f;
            uA[jj] = h2[(size_t)colA * 64 + lane];
            const unsigned colB = (j < dgB)
                ? (unsigned)__builtin_amdgcn_readlane((int)cBv, j) : 0u;
            vB[jj] = (j < dgB)
                ? __uint_as_float((unsigned)__builtin_amdgcn_readlane((int)wBv, j)) : 0.f;
            uB[jj] = h2[(size_t)colB * 64 + lane];
        }
#pragma unroll
        for (int jj = 0; jj < 8; ++jj) {
            axA += __uint_as_float(uA[jj] << 16) * vA[jj];
            ayA += __uint_as_float(uA[jj] & 0xFFFF0000u) * vA[jj];
            axB += __uint_as_float(uB[jj] << 16) * vB[jj];
            ayB += __uint_as_float(uB[jj] & 0xFFFF0000u) * vB[jj];
        }
    }

    const float2 bv = ((const float2*)b)[lane];
    floatx2 oA, oB;
    oA.x = fmaxf(axA + bv.x, 0.f);
    oA.y = fmaxf(ayA + bv.y, 0.f);
    oB.x = fmaxf(axB + bv.x, 0.f);
    oB.y = fmaxf(ayB + bv.y, 0.f);
    __builtin_nontemporal_store(oA, (floatx2*)(out + (size_t)rA * D) + lane);
    __builtin_nontemporal_store(oB, (floatx2*)(out + (size_t)rB * D) + lane);
}

extern "C" void kernel_launch(void* const* d_in, const int* in_sizes, int n_in,
                              void* d_out, int out_size, void* d_ws, size_t ws_size,
                              hipStream_t stream) {
    const float* x    = (const float*)d_in[0];
    const float* w    = (const float*)d_in[1];
    const float* b    = (const float*)d_in[2];
    const int*   erow = (const int*)d_in[3];
    const int*   ecol = (const int*)d_in[4];
    const float* eval = (const float*)d_in[5];
    const float* mask = (const float*)d_in[6];
    float* out = (float*)d_out;

    // workspace layout, total 64.4 MB
    char* base = (char*)d_ws;
    unsigned short* h = (unsigned short*)(base);                        // 25,600,000 B (bf16)
    int* deg          = (int*)(base + 25600000);                        //    400,000 B
    unsigned long long* pairs = (unsigned long long*)(base + 26000000); // 38,400,000 B

    (void)hipMemsetAsync(deg, 0, N_NODES * sizeof(int), stream);

    gemm_hist_fill<<<TOTAL_NB, 256, 0, stream>>>(x, mask, w, h, erow, ecol, eval, deg, pairs);
    gather_kernel<<<N_NODES / 8, 256, 0, stream>>>((const unsigned*)h, deg, pairs, b, out);
}